// Round 15
// baseline (105.403 us; speedup 1.0000x reference)
//
#include <hip/hip_runtime.h>
#include <hip/hip_bf16.h>

// RingAttention world_size=1 == causal GQA attention.
// B=1, S=4096, H=8, KVH=2 (group 4), D=64. fp32 in/out, bf16 MFMA math.
// R15: single-buffered LDS (16.4 KB -> 8 blocks/CU residency) + CHUNK=4
//      (NTR=272, 2176 blocks = 8.5/CU fills it). R14 proved intra-block
//      pipelining is useless here (overlap comes from co-resident blocks);
//      the dbuf was spending LDS residency on nothing.

#define S_LEN 4096
#define H_Q   8
#define H_KV  2
#define DH    64
#define BN    64
#define NEG_BIG (-1e30f)
#define CS (0.125f * 1.44269504088896340736f)   // 1/sqrt(64) * log2(e)

#define CHUNK 4                           // k-tiles per chunk
#define NTR   272                         // sum over qt(0..31) of ceil((2qt+2)/4)
#define KB_SH (S_LEN * H_KV * DH)         // 524288 shorts (1 MB) each Kb/Vt
#define TILE_SH 4096                      // shorts per (kvh, tile): 64x64
#define KVH_SH  (S_LEN * DH)              // 262144 shorts per kvh plane
#define OB_SH    ((size_t)NTR * H_Q * 128 * DH)   // bf16 partials (~35.7 MB)
#define L_FLOATS ((size_t)NTR * H_Q * 128)
#define WS_NEED ((size_t)(2 * KB_SH) * 2 + OB_SH * 2 + L_FLOATS * 4)

typedef __attribute__((ext_vector_type(8))) short bf16x8;
typedef __attribute__((ext_vector_type(4))) short s16x4;
typedef __attribute__((ext_vector_type(4))) float f32x4;
typedef __attribute__((ext_vector_type(4))) unsigned int u32x4;

__device__ __forceinline__ short bf(float x) {
    return __builtin_bit_cast(short, __float2bfloat16(x));
}
__device__ __forceinline__ float fbf(short u) {
    return __builtin_bit_cast(float, ((unsigned int)(unsigned short)u) << 16);
}
// packed f32x2 -> bf16x2 (RNE), single VALU instruction on gfx950
__device__ __forceinline__ unsigned int cvtpk(float lo, float hi) {
    unsigned int r;
    asm("v_cvt_pk_bf16_f32 %0, %1, %2" : "=v"(r) : "v"(lo), "v"(hi));
    return r;
}
// async global->LDS, 16B per lane; LDS dest = (wave-uniform) lp + lane*16
__device__ __forceinline__ void gload16(const short* gp, short* lp) {
    __builtin_amdgcn_global_load_lds(
        (const __attribute__((address_space(1))) unsigned int*)gp,
        (__attribute__((address_space(3))) unsigned int*)lp, 16, 0, 0);
}

// blocks 0..511: Kb[kvh][tile][row][chunk^(row&7)] = bf16(K)  (tile-contig)
// blocks 512..639: Vt[kvh][tile][d][keychunk^(d&7)] = bf16(V^T), key-permuted
//   per 64-block: logical col 16q+4a+r holds key 16a+4q+r.
__global__ __launch_bounds__(256)
void ring_attn_prepass(const float* __restrict__ K, const float* __restrict__ V,
                       short* __restrict__ Kb, short* __restrict__ Vt) {
    const int b = blockIdx.x;
    const int t = threadIdx.x;
    if (b < 512) {
        const int i = (b * 256 + t) * 4;      // float index into K
        const int s   = i >> 7;
        const int kvh = (i >> 6) & 1;
        const int d   = i & 63;               // multiple of 4
        float4 kv = *(const float4*)(K + i);
        const int dst = kvh * KVH_SH + (s >> 6) * TILE_SH + (s & 63) * 64
                      + (((d >> 3) ^ (s & 7)) * 8) + (d & 7);
        *(unsigned int*)(Kb + dst)     = cvtpk(kv.x, kv.y);
        *(unsigned int*)(Kb + dst + 2) = cvtpk(kv.z, kv.w);
    } else {
        __shared__ short T[DH * 72];
        const int bb  = b - 512;
        const int kvh = bb >> 6;
        const int j   = bb & 63;
        const int s0  = j * 64;
        {
            const int r  = t >> 2;
            const int dq = (t & 3) * 16;
            const float* vp = V + ((s0 + r) * H_KV + kvh) * DH + dq;
            float4 a0 = *(const float4*)(vp);
            float4 a1 = *(const float4*)(vp + 4);
            float4 a2 = *(const float4*)(vp + 8);
            float4 a3 = *(const float4*)(vp + 12);
            float e[16] = {a0.x,a0.y,a0.z,a0.w, a1.x,a1.y,a1.z,a1.w,
                           a2.x,a2.y,a2.z,a2.w, a3.x,a3.y,a3.z,a3.w};
#pragma unroll
            for (int i2 = 0; i2 < 16; ++i2)
                T[(dq + i2) * 72 + r] = bf(e[i2]);
        }
        __syncthreads();
        {
            const int d = t >> 2;
            const int q = t & 3;
            s16x4 g0 = *(const s16x4*)(&T[d * 72 + 4 * q]);
            s16x4 g1 = *(const s16x4*)(&T[d * 72 + 16 + 4 * q]);
            s16x4 g2 = *(const s16x4*)(&T[d * 72 + 32 + 4 * q]);
            s16x4 g3 = *(const s16x4*)(&T[d * 72 + 48 + 4 * q]);
            bf16x8 x0 = bf16x8{g0[0],g0[1],g0[2],g0[3], g1[0],g1[1],g1[2],g1[3]};
            bf16x8 x1 = bf16x8{g2[0],g2[1],g2[2],g2[3], g3[0],g3[1],g3[2],g3[3]};
            short* base = Vt + kvh * KVH_SH + j * TILE_SH + d * 64;
            *(bf16x8*)(base + ((2 * q)     ^ (d & 7)) * 8) = x0;
            *(bf16x8*)(base + ((2 * q + 1) ^ (d & 7)) * 8) = x1;
        }
    }
}

template <bool SPLIT>
__global__ __launch_bounds__(256, 4)
void ring_attn_fwd(const float* __restrict__ Q, const short* __restrict__ Kb,
                   const short* __restrict__ Vt, float* __restrict__ O,
                   short* __restrict__ Obuf, float* __restrict__ Lbuf) {
    const int bid = blockIdx.x;
    const int h   = bid & 7;
    int qt, nch, jbeg, jend, tr0;
    if (SPLIT) {
        const int tr = (NTR - 1) - (bid >> 3);   // heavy chunks dispatch first
        int g = 0, base = 0;
        for (;;) {   // group g: qt in {2g, 2g+1}, nch = g+1, count = 2(g+1)
            const int cnt2 = 2 * (g + 1);
            if (tr < base + cnt2) break;
            base += cnt2; ++g;
        }
        const int u  = tr - base;
        const int qq = u / (g + 1);
        const int ch = u - qq * (g + 1);
        qt   = 2 * g + qq;
        nch  = g + 1;
        tr0  = base + qq * (g + 1);
        jbeg = ch * CHUNK;
        jend = min(2 * qt + 2, jbeg + CHUNK);
    } else {
        qt = 31 - (bid >> 3);
        nch = 1; jbeg = 0; jend = 2 * qt + 2; tr0 = 0;
    }
    const int kvh = h >> 2;

    __shared__ short Ksb[4096];         // K tile image (swizzled), single buf
    __shared__ short Vsb[4096];         // V tile image (swizzled), single buf

    const int tid  = threadIdx.x;
    const int w    = tid >> 6;
    const int lane = tid & 63;
    const int c    = lane & 15;
    const int q    = lane >> 4;
    const int e    = c & 7;

    // ---- Q frags for 2 strips (B-operand: B[k=d=q*8+j][n=qrow=c]), CS-scaled ----
    bf16x8 qf[2][2];
#pragma unroll
    for (int st = 0; st < 2; ++st) {
        const int qg = qt * 128 + st * 64 + w * 16 + c;
        const float* qp = Q + (qg * H_Q + h) * DH + q * 8;
        float4 a0 = *(const float4*)(qp);
        float4 a1 = *(const float4*)(qp + 4);
        float4 b0 = *(const float4*)(qp + 32);
        float4 b1 = *(const float4*)(qp + 36);
        u32x4 u0 = {cvtpk(a0.x*CS, a0.y*CS), cvtpk(a0.z*CS, a0.w*CS),
                    cvtpk(a1.x*CS, a1.y*CS), cvtpk(a1.z*CS, a1.w*CS)};
        u32x4 u1 = {cvtpk(b0.x*CS, b0.y*CS), cvtpk(b0.z*CS, b0.w*CS),
                    cvtpk(b1.x*CS, b1.y*CS), cvtpk(b1.z*CS, b1.w*CS)};
        qf[st][0] = __builtin_bit_cast(bf16x8, u0);
        qf[st][1] = __builtin_bit_cast(bf16x8, u1);
    }

    f32x4 acc[2][4] = {};
    float l_a[2] = {0.f, 0.f}, l_b[2] = {0.f, 0.f};   // 2 chains per strip (ILP)

    // ---- async staging: wave w moves shorts [w*1024, w*1024+1024) of each tile ----
    const short* gkb = Kb + kvh * KVH_SH + w * 1024 + lane * 8;
    const short* gvb = Vt + kvh * KVH_SH + w * 1024 + lane * 8;

    for (int j = jbeg; j < jend; ++j) {
        {   // stage tile j (async DMA; __syncthreads below drains vmcnt)
            const short* gk = gkb + j * TILE_SH;
            const short* gv = gvb + j * TILE_SH;
            short* lk = &Ksb[w * 1024];
            short* lv = &Vsb[w * 1024];
            gload16(gk, lk);        gload16(gk + 512, lk + 512);
            gload16(gv, lv);        gload16(gv + 512, lv + 512);
        }
        __syncthreads();   // DMA landed, all waves staged

        // ---- S^T = K Q^T, joint strips (kf read once) ----
        f32x4 s[2][4] = {};
#pragma unroll
        for (int nt = 0; nt < 4; ++nt) {
            const int rb = (nt * 16 + c) * 64;
            bf16x8 kf0 = *(const bf16x8*)(Ksb + rb + (q ^ e) * 8);
            bf16x8 kf1 = *(const bf16x8*)(Ksb + rb + ((q + 4) ^ e) * 8);
            s[0][nt] = __builtin_amdgcn_mfma_f32_16x16x32_bf16(kf0, qf[0][0], s[0][nt], 0, 0, 0);
            s[0][nt] = __builtin_amdgcn_mfma_f32_16x16x32_bf16(kf1, qf[0][1], s[0][nt], 0, 0, 0);
            s[1][nt] = __builtin_amdgcn_mfma_f32_16x16x32_bf16(kf0, qf[1][0], s[1][nt], 0, 0, 0);
            s[1][nt] = __builtin_amdgcn_mfma_f32_16x16x32_bf16(kf1, qf[1][1], s[1][nt], 0, 0, 0);
        }

        bf16x8 pf[2][2];
#pragma unroll
        for (int st = 0; st < 2; ++st) {
            // ---- causal mask: j==2qt+st strip-diag; j>2qt+st fully masked ----
            if (j >= 2 * qt + st) {
                const int koff = (j - 2 * qt - st) * 64;
                const int qrl  = w * 16 + c;
#pragma unroll
                for (int nt = 0; nt < 4; ++nt) {
                    const int kl = koff + nt * 16 + q * 4;
#pragma unroll
                    for (int r = 0; r < 4; ++r)
                        if (kl + r > qrl) s[st][nt][r] = NEG_BIG;
                }
            }
            // ---- static-max softmax: raw v_exp_f32, 2 accumulation chains ----
#pragma unroll
            for (int nt = 0; nt < 4; ++nt)
#pragma unroll
                for (int r = 0; r < 4; ++r) {
                    const float p = __builtin_amdgcn_exp2f(s[st][nt][r]);
                    s[st][nt][r] = p;
                    if (nt & 1) l_b[st] += p; else l_a[st] += p;
                }
            // ---- P A-frags from own registers (packed cvt) ----
            u32x4 w0 = {cvtpk(s[st][0][0], s[st][0][1]), cvtpk(s[st][0][2], s[st][0][3]),
                        cvtpk(s[st][1][0], s[st][1][1]), cvtpk(s[st][1][2], s[st][1][3])};
            u32x4 w1 = {cvtpk(s[st][2][0], s[st][2][1]), cvtpk(s[st][2][2], s[st][2][3]),
                        cvtpk(s[st][3][0], s[st][3][1]), cvtpk(s[st][3][2], s[st][3][3])};
            pf[st][0] = __builtin_bit_cast(bf16x8, w0);
            pf[st][1] = __builtin_bit_cast(bf16x8, w1);
        }

        // ---- O += P V: vf b128 reads (swizzled, key-permuted), shared strips ----
#pragma unroll
        for (int dt = 0; dt < 4; ++dt) {
            const int nb = (dt * 16 + c) * 64;
            bf16x8 vf0 = *(const bf16x8*)(Vsb + nb + ((2 * q)     ^ e) * 8);
            bf16x8 vf1 = *(const bf16x8*)(Vsb + nb + ((2 * q + 1) ^ e) * 8);
            acc[0][dt] = __builtin_amdgcn_mfma_f32_16x16x32_bf16(pf[0][0], vf0, acc[0][dt], 0, 0, 0);
            acc[0][dt] = __builtin_amdgcn_mfma_f32_16x16x32_bf16(pf[0][1], vf1, acc[0][dt], 0, 0, 0);
            acc[1][dt] = __builtin_amdgcn_mfma_f32_16x16x32_bf16(pf[1][0], vf0, acc[1][dt], 0, 0, 0);
            acc[1][dt] = __builtin_amdgcn_mfma_f32_16x16x32_bf16(pf[1][1], vf1, acc[1][dt], 0, 0, 0);
        }
        __syncthreads();   // LDS reads done before next tile's DMA overwrites
    }

    // ---- l row sums (reduce over q), per strip ----
    float lr[2][4], l_lane[2];
#pragma unroll
    for (int st = 0; st < 2; ++st) {
        float t2 = l_a[st] + l_b[st];
        t2 += __shfl_xor(t2, 16);
        t2 += __shfl_xor(t2, 32);
        l_lane[st] = t2;
#pragma unroll
        for (int r = 0; r < 4; ++r)
            lr[st][r] = __shfl(t2, q * 4 + r);
    }

    if (!SPLIT || nch == 1) {
#pragma unroll
        for (int st = 0; st < 2; ++st)
#pragma unroll
            for (int r = 0; r < 4; ++r) {
                const float inv = 1.0f / lr[st][r];
                const int row = qt * 128 + st * 64 + w * 16 + q * 4 + r;
                float* op = O + (row * H_Q + h) * DH + c;
#pragma unroll
                for (int dt = 0; dt < 4; ++dt)
                    op[dt * 16] = acc[st][dt][r] * inv;
            }
    } else {
        const int slot = (tr0 + jbeg / CHUNK) * 8 + h;
        short* ob = Obuf + (size_t)slot * (128 * DH);
#pragma unroll
        for (int st = 0; st < 2; ++st) {
#pragma unroll
            for (int r = 0; r < 4; ++r) {
                const int rin = st * 64 + w * 16 + q * 4 + r;
#pragma unroll
                for (int dt = 0; dt < 4; ++dt)
                    ob[rin * DH + dt * 16 + c] = bf(acc[st][dt][r]);
            }
            if (lane < 16)
                Lbuf[slot * 128 + st * 64 + w * 16 + lane] = l_lane[st];
        }
    }
}

// merge chunk partials for qt >= 2 (rows >= 256); 8 d-elems per thread
__global__ __launch_bounds__(256)
void ring_attn_combine(const short* __restrict__ Obuf, const float* __restrict__ Lbuf,
                       float* __restrict__ O) {
    const int gid  = blockIdx.x * 256 + threadIdx.x;
    const int d0   = (gid & 7) * 8;
    const int h    = (gid >> 3) & 7;
    const int srow = 256 + (gid >> 6);
    const int qt   = srow >> 7;
    const int rin  = srow & 127;
    const int g    = qt >> 1;                      // 1..15
    const int base = g * (g + 1);
    const int nch  = g + 1;
    const int tr0  = base + (qt & 1) * nch;

    float num[8] = {};
    float den = 0.0f;
    for (int ch = 0; ch < nch; ++ch) {
        const int slot = (tr0 + ch) * 8 + h;
        den += Lbuf[slot * 128 + rin];
        bf16x8 v = *(const bf16x8*)(Obuf + (size_t)slot * (128 * DH) + rin * DH + d0);
#pragma unroll
        for (int i = 0; i < 8; ++i)
            num[i] += fbf(v[i]);
    }
    const float inv = 1.0f / den;
    float* op = O + (srow * H_Q + h) * DH + d0;
    *(float4*)(op)     = float4{num[0]*inv, num[1]*inv, num[2]*inv, num[3]*inv};
    *(float4*)(op + 4) = float4{num[4]*inv, num[5]*inv, num[6]*inv, num[7]*inv};
}

extern "C" void kernel_launch(void* const* d_in, const int* in_sizes, int n_in,
                              void* d_out, int out_size, void* d_ws, size_t ws_size,
                              hipStream_t stream) {
    const float* Q = (const float*)d_in[0];
    const float* K = (const float*)d_in[1];
    const float* V = (const float*)d_in[2];
    float* O  = (float*)d_out;
    short* Kb = (short*)d_ws;
    short* Vt = Kb + KB_SH;
    short* Obuf = Vt + KB_SH;
    float* Lbuf = (float*)(Obuf + OB_SH);

    ring_attn_prepass<<<640, 256, 0, stream>>>(K, V, Kb, Vt);
    if (ws_size >= WS_NEED) {
        ring_attn_fwd<true><<<NTR * H_Q, 256, 0, stream>>>(Q, Kb, Vt, O, Obuf, Lbuf);
        ring_attn_combine<<<(S_LEN - 256) * H_Q * DH / 8 / 256, 256, 0, stream>>>(Obuf, Lbuf, O);
    } else {
        ring_attn_fwd<false><<<32 * H_Q, 256, 0, stream>>>(Q, Kb, Vt, O, Obuf, Lbuf);
    }
}

// Round 16
// 100.950 us; speedup vs baseline: 1.0441x; 1.0441x over previous
//
#include <hip/hip_runtime.h>
#include <hip/hip_bf16.h>

// RingAttention world_size=1 == causal GQA attention.
// B=1, S=4096, H=8, KVH=2 (group 4), D=64. fp32 in/out, bf16 MFMA math.
// R16 == R13 (best measured: 100.9 us): CHUNK=8 split-KV, dbuf LDS via
//      global_load_lds from tile-contiguous XOR-swizzled bf16 Kb/Vt,
//      S^T-trick register-P, joint-strip QK, vectorized combine.
//      R14 (raw-barrier vmcnt) neutral; R15 (single-buf, CHUNK=4) regressed
//      -> this config is the empirical optimum of the structure.

#define S_LEN 4096
#define H_Q   8
#define H_KV  2
#define DH    64
#define BN    64
#define NEG_BIG (-1e30f)
#define CS (0.125f * 1.44269504088896340736f)   // 1/sqrt(64) * log2(e)

#define CHUNK 8                           // k-tiles per chunk
#define NTR   144                         // sum over qt(0..31) of ceil((2qt+2)/8)
#define KB_SH (S_LEN * H_KV * DH)         // 524288 shorts (1 MB) each Kb/Vt
#define TILE_SH 4096                      // shorts per (kvh, tile): 64x64
#define KVH_SH  (S_LEN * DH)              // 262144 shorts per kvh plane
#define OB_SH    ((size_t)NTR * H_Q * 128 * DH)   // bf16 partials
#define L_FLOATS ((size_t)NTR * H_Q * 128)
#define WS_NEED ((size_t)(2 * KB_SH) * 2 + OB_SH * 2 + L_FLOATS * 4)   // ~21.5 MB

typedef __attribute__((ext_vector_type(8))) short bf16x8;
typedef __attribute__((ext_vector_type(4))) short s16x4;
typedef __attribute__((ext_vector_type(4))) float f32x4;
typedef __attribute__((ext_vector_type(4))) unsigned int u32x4;

__device__ __forceinline__ short bf(float x) {
    return __builtin_bit_cast(short, __float2bfloat16(x));
}
__device__ __forceinline__ float fbf(short u) {
    return __builtin_bit_cast(float, ((unsigned int)(unsigned short)u) << 16);
}
// packed f32x2 -> bf16x2 (RNE), single VALU instruction on gfx950
__device__ __forceinline__ unsigned int cvtpk(float lo, float hi) {
    unsigned int r;
    asm("v_cvt_pk_bf16_f32 %0, %1, %2" : "=v"(r) : "v"(lo), "v"(hi));
    return r;
}
// async global->LDS, 16B per lane; LDS dest = (wave-uniform) lp + lane*16
__device__ __forceinline__ void gload16(const short* gp, short* lp) {
    __builtin_amdgcn_global_load_lds(
        (const __attribute__((address_space(1))) unsigned int*)gp,
        (__attribute__((address_space(3))) unsigned int*)lp, 16, 0, 0);
}

// blocks 0..511: Kb[kvh][tile][row][chunk^(row&7)] = bf16(K)  (tile-contig)
// blocks 512..639: Vt[kvh][tile][d][keychunk^(d&7)] = bf16(V^T), key-permuted
//   per 64-block: logical col 16q+4a+r holds key 16a+4q+r.
__global__ __launch_bounds__(256)
void ring_attn_prepass(const float* __restrict__ K, const float* __restrict__ V,
                       short* __restrict__ Kb, short* __restrict__ Vt) {
    const int b = blockIdx.x;
    const int t = threadIdx.x;
    if (b < 512) {
        const int i = (b * 256 + t) * 4;      // float index into K
        const int s   = i >> 7;
        const int kvh = (i >> 6) & 1;
        const int d   = i & 63;               // multiple of 4
        float4 kv = *(const float4*)(K + i);
        const int dst = kvh * KVH_SH + (s >> 6) * TILE_SH + (s & 63) * 64
                      + (((d >> 3) ^ (s & 7)) * 8) + (d & 7);
        *(unsigned int*)(Kb + dst)     = cvtpk(kv.x, kv.y);
        *(unsigned int*)(Kb + dst + 2) = cvtpk(kv.z, kv.w);
    } else {
        __shared__ short T[DH * 72];
        const int bb  = b - 512;
        const int kvh = bb >> 6;
        const int j   = bb & 63;
        const int s0  = j * 64;
        {
            const int r  = t >> 2;
            const int dq = (t & 3) * 16;
            const float* vp = V + ((s0 + r) * H_KV + kvh) * DH + dq;
            float4 a0 = *(const float4*)(vp);
            float4 a1 = *(const float4*)(vp + 4);
            float4 a2 = *(const float4*)(vp + 8);
            float4 a3 = *(const float4*)(vp + 12);
            float e[16] = {a0.x,a0.y,a0.z,a0.w, a1.x,a1.y,a1.z,a1.w,
                           a2.x,a2.y,a2.z,a2.w, a3.x,a3.y,a3.z,a3.w};
#pragma unroll
            for (int i2 = 0; i2 < 16; ++i2)
                T[(dq + i2) * 72 + r] = bf(e[i2]);
        }
        __syncthreads();
        {
            const int d = t >> 2;
            const int q = t & 3;
            s16x4 g0 = *(const s16x4*)(&T[d * 72 + 4 * q]);
            s16x4 g1 = *(const s16x4*)(&T[d * 72 + 16 + 4 * q]);
            s16x4 g2 = *(const s16x4*)(&T[d * 72 + 32 + 4 * q]);
            s16x4 g3 = *(const s16x4*)(&T[d * 72 + 48 + 4 * q]);
            bf16x8 x0 = bf16x8{g0[0],g0[1],g0[2],g0[3], g1[0],g1[1],g1[2],g1[3]};
            bf16x8 x1 = bf16x8{g2[0],g2[1],g2[2],g2[3], g3[0],g3[1],g3[2],g3[3]};
            short* base = Vt + kvh * KVH_SH + j * TILE_SH + d * 64;
            *(bf16x8*)(base + ((2 * q)     ^ (d & 7)) * 8) = x0;
            *(bf16x8*)(base + ((2 * q + 1) ^ (d & 7)) * 8) = x1;
        }
    }
}

template <bool SPLIT>
__global__ __launch_bounds__(256, 4)
void ring_attn_fwd(const float* __restrict__ Q, const short* __restrict__ Kb,
                   const short* __restrict__ Vt, float* __restrict__ O,
                   short* __restrict__ Obuf, float* __restrict__ Lbuf) {
    const int bid = blockIdx.x;
    const int h   = bid & 7;
    int qt, nch, jbeg, jend, tr0;
    if (SPLIT) {
        const int tr = (NTR - 1) - (bid >> 3);   // heavy chunks dispatch first
        int g = 0, base = 0;
        for (;;) {   // group g: qt in [4g, 4g+3], nch = g+1, count = 4(g+1)
            const int cnt2 = 4 * (g + 1);
            if (tr < base + cnt2) break;
            base += cnt2; ++g;
        }
        const int u  = tr - base;
        const int qq = u / (g + 1);
        const int ch = u - qq * (g + 1);
        qt   = 4 * g + qq;
        nch  = g + 1;
        tr0  = base + qq * (g + 1);
        jbeg = ch * CHUNK;
        jend = min(2 * qt + 2, jbeg + CHUNK);
    } else {
        qt = 31 - (bid >> 3);
        nch = 1; jbeg = 0; jend = 2 * qt + 2; tr0 = 0;
    }
    const int kvh = h >> 2;

    __shared__ short Ksb[2][4096];      // K tile image (swizzled), dbuf
    __shared__ short Vsb[2][4096];      // V tile image (swizzled), dbuf

    const int tid  = threadIdx.x;
    const int w    = tid >> 6;
    const int lane = tid & 63;
    const int c    = lane & 15;
    const int q    = lane >> 4;
    const int e    = c & 7;

    // ---- Q frags for 2 strips (B-operand: B[k=d=q*8+j][n=qrow=c]), CS-scaled ----
    bf16x8 qf[2][2];
#pragma unroll
    for (int st = 0; st < 2; ++st) {
        const int qg = qt * 128 + st * 64 + w * 16 + c;
        const float* qp = Q + (qg * H_Q + h) * DH + q * 8;
        float4 a0 = *(const float4*)(qp);
        float4 a1 = *(const float4*)(qp + 4);
        float4 b0 = *(const float4*)(qp + 32);
        float4 b1 = *(const float4*)(qp + 36);
        u32x4 u0 = {cvtpk(a0.x*CS, a0.y*CS), cvtpk(a0.z*CS, a0.w*CS),
                    cvtpk(a1.x*CS, a1.y*CS), cvtpk(a1.z*CS, a1.w*CS)};
        u32x4 u1 = {cvtpk(b0.x*CS, b0.y*CS), cvtpk(b0.z*CS, b0.w*CS),
                    cvtpk(b1.x*CS, b1.y*CS), cvtpk(b1.z*CS, b1.w*CS)};
        qf[st][0] = __builtin_bit_cast(bf16x8, u0);
        qf[st][1] = __builtin_bit_cast(bf16x8, u1);
    }

    f32x4 acc[2][4] = {};
    float l_a[2] = {0.f, 0.f}, l_b[2] = {0.f, 0.f};   // 2 chains per strip (ILP)

    // ---- async staging: wave w moves shorts [w*1024, w*1024+1024) of each tile ----
    const short* gkb = Kb + kvh * KVH_SH + w * 1024 + lane * 8;
    const short* gvb = Vt + kvh * KVH_SH + w * 1024 + lane * 8;
#define STAGE(buf, j)                                             \
    do {                                                          \
        const short* gk = gkb + (j) * TILE_SH;                    \
        const short* gv = gvb + (j) * TILE_SH;                    \
        short* lk = &Ksb[buf][w * 1024];                          \
        short* lv = &Vsb[buf][w * 1024];                          \
        gload16(gk, lk);        gload16(gk + 512, lk + 512);      \
        gload16(gv, lv);        gload16(gv + 512, lv + 512);      \
    } while (0)

    STAGE(0, jbeg);

    for (int j = jbeg; j < jend; ++j) {
        const int cur = (j - jbeg) & 1;
        __syncthreads();   // drains vmcnt: buf[cur] ready; prior LDS reads done
        if (j + 1 < jend)
            STAGE(cur ^ 1, j + 1);   // latency overlaps compute below

        const short* Kc = Ksb[cur];
        const short* Vc = Vsb[cur];

        // ---- S^T = K Q^T, joint strips (kf read once) ----
        f32x4 s[2][4] = {};
#pragma unroll
        for (int nt = 0; nt < 4; ++nt) {
            const int rb = (nt * 16 + c) * 64;
            bf16x8 kf0 = *(const bf16x8*)(Kc + rb + (q ^ e) * 8);
            bf16x8 kf1 = *(const bf16x8*)(Kc + rb + ((q + 4) ^ e) * 8);
            s[0][nt] = __builtin_amdgcn_mfma_f32_16x16x32_bf16(kf0, qf[0][0], s[0][nt], 0, 0, 0);
            s[0][nt] = __builtin_amdgcn_mfma_f32_16x16x32_bf16(kf1, qf[0][1], s[0][nt], 0, 0, 0);
            s[1][nt] = __builtin_amdgcn_mfma_f32_16x16x32_bf16(kf0, qf[1][0], s[1][nt], 0, 0, 0);
            s[1][nt] = __builtin_amdgcn_mfma_f32_16x16x32_bf16(kf1, qf[1][1], s[1][nt], 0, 0, 0);
        }

        bf16x8 pf[2][2];
#pragma unroll
        for (int st = 0; st < 2; ++st) {
            // ---- causal mask: j==2qt+st strip-diag; j>2qt+st fully masked ----
            if (j >= 2 * qt + st) {
                const int koff = (j - 2 * qt - st) * 64;
                const int qrl  = w * 16 + c;
#pragma unroll
                for (int nt = 0; nt < 4; ++nt) {
                    const int kl = koff + nt * 16 + q * 4;
#pragma unroll
                    for (int r = 0; r < 4; ++r)
                        if (kl + r > qrl) s[st][nt][r] = NEG_BIG;
                }
            }
            // ---- static-max softmax: raw v_exp_f32, 2 accumulation chains ----
#pragma unroll
            for (int nt = 0; nt < 4; ++nt)
#pragma unroll
                for (int r = 0; r < 4; ++r) {
                    const float p = __builtin_amdgcn_exp2f(s[st][nt][r]);
                    s[st][nt][r] = p;
                    if (nt & 1) l_b[st] += p; else l_a[st] += p;
                }
            // ---- P A-frags from own registers (packed cvt) ----
            u32x4 w0 = {cvtpk(s[st][0][0], s[st][0][1]), cvtpk(s[st][0][2], s[st][0][3]),
                        cvtpk(s[st][1][0], s[st][1][1]), cvtpk(s[st][1][2], s[st][1][3])};
            u32x4 w1 = {cvtpk(s[st][2][0], s[st][2][1]), cvtpk(s[st][2][2], s[st][2][3]),
                        cvtpk(s[st][3][0], s[st][3][1]), cvtpk(s[st][3][2], s[st][3][3])};
            pf[st][0] = __builtin_bit_cast(bf16x8, w0);
            pf[st][1] = __builtin_bit_cast(bf16x8, w1);
        }

        // ---- O += P V: vf b128 reads (swizzled, key-permuted), shared strips ----
#pragma unroll
        for (int dt = 0; dt < 4; ++dt) {
            const int nb = (dt * 16 + c) * 64;
            bf16x8 vf0 = *(const bf16x8*)(Vc + nb + ((2 * q)     ^ e) * 8);
            bf16x8 vf1 = *(const bf16x8*)(Vc + nb + ((2 * q + 1) ^ e) * 8);
            acc[0][dt] = __builtin_amdgcn_mfma_f32_16x16x32_bf16(pf[0][0], vf0, acc[0][dt], 0, 0, 0);
            acc[0][dt] = __builtin_amdgcn_mfma_f32_16x16x32_bf16(pf[0][1], vf1, acc[0][dt], 0, 0, 0);
            acc[1][dt] = __builtin_amdgcn_mfma_f32_16x16x32_bf16(pf[1][0], vf0, acc[1][dt], 0, 0, 0);
            acc[1][dt] = __builtin_amdgcn_mfma_f32_16x16x32_bf16(pf[1][1], vf1, acc[1][dt], 0, 0, 0);
        }
    }

    // ---- l row sums (reduce over q), per strip ----
    float lr[2][4], l_lane[2];
#pragma unroll
    for (int st = 0; st < 2; ++st) {
        float t2 = l_a[st] + l_b[st];
        t2 += __shfl_xor(t2, 16);
        t2 += __shfl_xor(t2, 32);
        l_lane[st] = t2;
#pragma unroll
        for (int r = 0; r < 4; ++r)
            lr[st][r] = __shfl(t2, q * 4 + r);
    }

    if (!SPLIT || nch == 1) {
#pragma unroll
        for (int st = 0; st < 2; ++st)
#pragma unroll
            for (int r = 0; r < 4; ++r) {
                const float inv = 1.0f / lr[st][r];
                const int row = qt * 128 + st * 64 + w * 16 + q * 4 + r;
                float* op = O + (row * H_Q + h) * DH + c;
#pragma unroll
                for (int dt = 0; dt < 4; ++dt)
                    op[dt * 16] = acc[st][dt][r] * inv;
            }
    } else {
        const int slot = (tr0 + jbeg / CHUNK) * 8 + h;
        short* ob = Obuf + (size_t)slot * (128 * DH);
#pragma unroll
        for (int st = 0; st < 2; ++st) {
#pragma unroll
            for (int r = 0; r < 4; ++r) {
                const int rin = st * 64 + w * 16 + q * 4 + r;
#pragma unroll
                for (int dt = 0; dt < 4; ++dt)
                    ob[rin * DH + dt * 16 + c] = bf(acc[st][dt][r]);
            }
            if (lane < 16)
                Lbuf[slot * 128 + st * 64 + w * 16 + lane] = l_lane[st];
        }
    }
}

// merge chunk partials for qt >= 4 (rows >= 512); 8 d-elems per thread
__global__ __launch_bounds__(256)
void ring_attn_combine(const short* __restrict__ Obuf, const float* __restrict__ Lbuf,
                       float* __restrict__ O) {
    const int gid  = blockIdx.x * 256 + threadIdx.x;
    const int d0   = (gid & 7) * 8;
    const int h    = (gid >> 3) & 7;
    const int srow = 512 + (gid >> 6);
    const int qt   = srow >> 7;
    const int rin  = srow & 127;
    const int g    = qt >> 2;                      // 1..7
    const int base = 2 * g * (g + 1);
    const int nch  = g + 1;
    const int tr0  = base + (qt - 4 * g) * nch;

    float num[8] = {};
    float den = 0.0f;
    for (int ch = 0; ch < nch; ++ch) {
        const int slot = (tr0 + ch) * 8 + h;
        den += Lbuf[slot * 128 + rin];
        bf16x8 v = *(const bf16x8*)(Obuf + (size_t)slot * (128 * DH) + rin * DH + d0);
#pragma unroll
        for (int i = 0; i < 8; ++i)
            num[i] += fbf(v[i]);
    }
    const float inv = 1.0f / den;
    float* op = O + (srow * H_Q + h) * DH + d0;
    *(float4*)(op)     = float4{num[0]*inv, num[1]*inv, num[2]*inv, num[3]*inv};
    *(float4*)(op + 4) = float4{num[4]*inv, num[5]*inv, num[6]*inv, num[7]*inv};
}

extern "C" void kernel_launch(void* const* d_in, const int* in_sizes, int n_in,
                              void* d_out, int out_size, void* d_ws, size_t ws_size,
                              hipStream_t stream) {
    const float* Q = (const float*)d_in[0];
    const float* K = (const float*)d_in[1];
    const float* V = (const float*)d_in[2];
    float* O  = (float*)d_out;
    short* Kb = (short*)d_ws;
    short* Vt = Kb + KB_SH;
    short* Obuf = Vt + KB_SH;
    float* Lbuf = (float*)(Obuf + OB_SH);

    ring_attn_prepass<<<640, 256, 0, stream>>>(K, V, Kb, Vt);
    if (ws_size >= WS_NEED) {
        ring_attn_fwd<true><<<NTR * H_Q, 256, 0, stream>>>(Q, Kb, Vt, O, Obuf, Lbuf);
        ring_attn_combine<<<(S_LEN - 512) * H_Q * DH / 8 / 256, 256, 0, stream>>>(Obuf, Lbuf, O);
    } else {
        ring_attn_fwd<false><<<32 * H_Q, 256, 0, stream>>>(Q, Kb, Vt, O, Obuf, Lbuf);
    }
}